// Round 5
// baseline (2844.752 us; speedup 1.0000x reference)
//
#include <hip/hip_runtime.h>

// GCN 2-layer + head — bin-decomposed, zero global atomics.
// Edges binned by dst>>7 (128-node bins, 782 bins). Per-bin LDS f32
// accumulation replaces CSR gather; LDS atomics replace all global atomics.
// bucket word = (src<<7) | (dst&127)  (src < 2^17, so fits in 24 bits).

#define HID 64
#define INC 11
#define BINSH 7
#define BINW 128
#define MAXNB 800      // >= ceil(100000/128)=782
#define ECHUNK 16384
#define SCAN_CHUNK 1024

// ---- A1: per-chunk histogram of dst bins, stored transposed histT[b*C+c] ----
__global__ void k_hist(const int* __restrict__ dst, int E, int C, int NB,
                       int* __restrict__ histT) {
    __shared__ int h[MAXNB];
    int c = blockIdx.x, t = threadIdx.x;
    for (int i = t; i < NB; i += 256) h[i] = 0;
    __syncthreads();
    int base = c * ECHUNK;
    int end = min(base + ECHUNK, E);
    for (int i = base + t; i < end; i += 256)
        atomicAdd(&h[dst[i] >> BINSH], 1);
    __syncthreads();
    for (int b = t; b < NB; b += 256)
        histT[(size_t)b * C + c] = h[b];
}

// ---- generic 3-kernel exclusive scan (length L <= 256*SCAN_CHUNK) ----
__global__ void k_scan1(const int* __restrict__ in, int L,
                        int* __restrict__ part, int* __restrict__ blocksums) {
    __shared__ int lds[SCAN_CHUNK];
    __shared__ int tsum[256];
    int b = blockIdx.x, t = threadIdx.x;
    int base = b * SCAN_CHUNK;
    for (int i = t; i < SCAN_CHUNK; i += 256)
        lds[i] = (base + i < L) ? in[base + i] : 0;
    __syncthreads();
    int a0 = lds[t*4], a1 = lds[t*4+1], a2 = lds[t*4+2], a3 = lds[t*4+3];
    int ts = a0 + a1 + a2 + a3;
    tsum[t] = ts;
    __syncthreads();
    for (int off = 1; off < 256; off <<= 1) {
        int v = (t >= off) ? tsum[t - off] : 0;
        __syncthreads();
        tsum[t] += v;
        __syncthreads();
    }
    int excl = tsum[t] - ts;
    int i0 = base + t*4;
    if (i0     < L) part[i0]     = excl;
    if (i0 + 1 < L) part[i0 + 1] = excl + a0;
    if (i0 + 2 < L) part[i0 + 2] = excl + a0 + a1;
    if (i0 + 3 < L) part[i0 + 3] = excl + a0 + a1 + a2;
    if (t == 255) blocksums[b] = tsum[255];
}

__global__ void k_scan2(const int* __restrict__ blocksums, int nb, int* __restrict__ blockoff) {
    __shared__ int s[256];
    int t = threadIdx.x;
    s[t] = (t < nb) ? blocksums[t] : 0;
    __syncthreads();
    int mine = s[t];
    for (int off = 1; off < 256; off <<= 1) {
        int v = (t >= off) ? s[t - off] : 0;
        __syncthreads();
        s[t] += v;
        __syncthreads();
    }
    blockoff[t] = s[t] - mine;   // exclusive
}

__global__ void k_scan3f(int* __restrict__ part, const int* __restrict__ blockoff, int L) {
    int i = blockIdx.x * blockDim.x + threadIdx.x;
    if (i < L) part[i] += blockoff[i / SCAN_CHUNK];
}

__global__ void k_binbase(const int* __restrict__ scanT, int C, int NB, int E,
                          int* __restrict__ binBase) {
    int b = blockIdx.x * blockDim.x + threadIdx.x;
    if (b < NB) binBase[b] = scanT[(size_t)b * C];
    else if (b == NB) binBase[NB] = E;
}

// ---- A3: scatter edges into bins; rank via LDS atomic, plain global store ----
__global__ void k_scatterbin(const int* __restrict__ src, const int* __restrict__ dst,
                             int E, int C, int NB, const int* __restrict__ scanT,
                             int* __restrict__ bucket) {
    __shared__ int cur[MAXNB];
    int c = blockIdx.x, t = threadIdx.x;
    for (int b = t; b < NB; b += 256) cur[b] = scanT[(size_t)b * C + c];
    __syncthreads();
    int base = c * ECHUNK;
    int end = min(base + ECHUNK, E);
    for (int i = base + t; i < end; i += 256) {
        int d = dst[i];
        int r = atomicAdd(&cur[d >> BINSH], 1);
        bucket[r] = (src[i] << BINSH) | (d & (BINW - 1));
    }
}

// ---- per-bin degree -> dis = rsqrt(deg+1) ----
__global__ void k_bindeg(const int* __restrict__ binBase, const int* __restrict__ bucket,
                         float* __restrict__ dis, int N) {
    __shared__ int cnt[BINW];
    int b = blockIdx.x, t = threadIdx.x;
    if (t < BINW) cnt[t] = 0;
    __syncthreads();
    int s = binBase[b], e = binBase[b + 1];
    for (int p = s + t; p < e; p += 256)
        atomicAdd(&cnt[bucket[p] & (BINW - 1)], 1);
    __syncthreads();
    if (t < BINW) {
        int n = b * BINW + t;
        if (n < N) dis[n] = rsqrtf((float)(cnt[t] + 1));
    }
}

// ---- g[N,64] = dis[row] * (x[N,11] @ W1[11,64]) ----
__global__ void k_xw1(const float* __restrict__ x, const float* __restrict__ W1,
                      const float* __restrict__ dis, float* __restrict__ g, int N) {
    __shared__ float Ws[INC * HID];
    int t = threadIdx.x;
    for (int i = t; i < INC * HID; i += blockDim.x) Ws[i] = W1[i];
    __syncthreads();
    int c = t & 63;
    for (int row = blockIdx.x * 4 + (t >> 6); row < N; row += gridDim.x * 4) {
        float acc = 0.f;
        #pragma unroll
        for (int k = 0; k < INC; ++k) acc += x[row * INC + k] * Ws[k * HID + c];
        g[row * HID + c] = dis[row] * acc;
    }
}

// ---- g2[N,64] = dis[row] * (a[N,64] @ W2[64,64]), persistent blocks ----
__global__ void k_xw2(const float* __restrict__ in, const float* __restrict__ W2,
                      const float* __restrict__ dis, float* __restrict__ g, int N) {
    __shared__ float Ws[HID * HID];
    int t = threadIdx.x;
    for (int i = t; i < HID * HID; i += blockDim.x) Ws[i] = W2[i];
    __syncthreads();
    int c = t & 63;
    for (int row = blockIdx.x * 4 + (t >> 6); row < N; row += gridDim.x * 4) {
        const float* r = in + row * HID;
        float acc = 0.f;
        #pragma unroll
        for (int k = 0; k < HID; k += 4) {
            float4 rv = *(const float4*)(r + k);
            acc += rv.x * Ws[(k    ) * HID + c];
            acc += rv.y * Ws[(k + 1) * HID + c];
            acc += rv.z * Ws[(k + 2) * HID + c];
            acc += rv.w * Ws[(k + 3) * HID + c];
        }
        g[row * HID + c] = dis[row] * acc;
    }
}

// ---- per-bin aggregation into LDS, layer 1 epilogue ----
__global__ void k_aggbin1(const int* __restrict__ binBase, const int* __restrict__ bucket,
                          const float* __restrict__ g, const float* __restrict__ dis,
                          const float* __restrict__ bias, float* __restrict__ outA, int N) {
    __shared__ float acc[BINW * HID];   // 32 KB
    int t = threadIdx.x, b = blockIdx.x;
    int lane = t & 63, wv = t >> 6;     // 8 waves
    for (int i = t; i < BINW * HID; i += 512) acc[i] = 0.f;
    __syncthreads();
    int s = binBase[b], e = binBase[b + 1];
    // 4 independent gathers in flight per wave
    for (int p = s + wv * 4; p < e; p += 32) {
        int w0 = bucket[p];
        int w1 = (p + 1 < e) ? bucket[p + 1] : -1;
        int w2 = (p + 2 < e) ? bucket[p + 2] : -1;
        int w3 = (p + 3 < e) ? bucket[p + 3] : -1;
        float v0 = g[(size_t)(w0 >> BINSH) * HID + lane];
        float v1 = (w1 >= 0) ? g[(size_t)(w1 >> BINSH) * HID + lane] : 0.f;
        float v2 = (w2 >= 0) ? g[(size_t)(w2 >> BINSH) * HID + lane] : 0.f;
        float v3 = (w3 >= 0) ? g[(size_t)(w3 >> BINSH) * HID + lane] : 0.f;
        atomicAdd(&acc[(w0 & (BINW - 1)) * HID + lane], v0);
        if (w1 >= 0) atomicAdd(&acc[(w1 & (BINW - 1)) * HID + lane], v1);
        if (w2 >= 0) atomicAdd(&acc[(w2 & (BINW - 1)) * HID + lane], v2);
        if (w3 >= 0) atomicAdd(&acc[(w3 & (BINW - 1)) * HID + lane], v3);
    }
    __syncthreads();
    float bb = bias[lane];
    for (int r = wv; r < BINW; r += 8) {
        int n = b * BINW + r;
        if (n < N) {
            float v = dis[n] * (acc[r * HID + lane] + g[(size_t)n * HID + lane]) + bb;
            outA[(size_t)n * HID + lane] = v > 0.f ? v : 0.f;
        }
    }
}

// ---- per-bin aggregation, layer 2 + fused linear head ----
__global__ void k_aggbin2_head(const int* __restrict__ binBase, const int* __restrict__ bucket,
                               const float* __restrict__ g, const float* __restrict__ dis,
                               const float* __restrict__ bias, const float* __restrict__ Wl,
                               const float* __restrict__ bl, float* __restrict__ out, int N) {
    __shared__ float acc[BINW * HID];   // 32 KB
    int t = threadIdx.x, b = blockIdx.x;
    int lane = t & 63, wv = t >> 6;
    for (int i = t; i < BINW * HID; i += 512) acc[i] = 0.f;
    __syncthreads();
    int s = binBase[b], e = binBase[b + 1];
    for (int p = s + wv * 4; p < e; p += 32) {
        int w0 = bucket[p];
        int w1 = (p + 1 < e) ? bucket[p + 1] : -1;
        int w2 = (p + 2 < e) ? bucket[p + 2] : -1;
        int w3 = (p + 3 < e) ? bucket[p + 3] : -1;
        float v0 = g[(size_t)(w0 >> BINSH) * HID + lane];
        float v1 = (w1 >= 0) ? g[(size_t)(w1 >> BINSH) * HID + lane] : 0.f;
        float v2 = (w2 >= 0) ? g[(size_t)(w2 >> BINSH) * HID + lane] : 0.f;
        float v3 = (w3 >= 0) ? g[(size_t)(w3 >> BINSH) * HID + lane] : 0.f;
        atomicAdd(&acc[(w0 & (BINW - 1)) * HID + lane], v0);
        if (w1 >= 0) atomicAdd(&acc[(w1 & (BINW - 1)) * HID + lane], v1);
        if (w2 >= 0) atomicAdd(&acc[(w2 & (BINW - 1)) * HID + lane], v2);
        if (w3 >= 0) atomicAdd(&acc[(w3 & (BINW - 1)) * HID + lane], v3);
    }
    __syncthreads();
    float bb = bias[lane];
    float wl = Wl[lane];
    for (int r = wv; r < BINW; r += 8) {
        int n = b * BINW + r;
        if (n < N) {
            float v = dis[n] * (acc[r * HID + lane] + g[(size_t)n * HID + lane]) + bb;
            v = v > 0.f ? v : 0.f;
            v *= wl;
            #pragma unroll
            for (int off = 32; off > 0; off >>= 1) v += __shfl_down(v, off);
            if (lane == 0) out[n] = v + bl[0];
        }
    }
}

extern "C" void kernel_launch(void* const* d_in, const int* in_sizes, int n_in,
                              void* d_out, int out_size, void* d_ws, size_t ws_size,
                              hipStream_t stream) {
    const float* x  = (const float*)d_in[0];
    const int*   ei = (const int*)d_in[1];
    const float* W1 = (const float*)d_in[2];
    const float* b1 = (const float*)d_in[3];
    const float* W2 = (const float*)d_in[4];
    const float* b2 = (const float*)d_in[5];
    const float* Wl = (const float*)d_in[6];
    const float* bl = (const float*)d_in[7];
    float* out = (float*)d_out;

    const int N = in_sizes[0] / INC;    // 100000
    const int E = in_sizes[1] / 2;      // 3200000
    const int NB = (N + BINW - 1) / BINW;        // 782
    const int C  = (E + ECHUNK - 1) / ECHUNK;    // 196
    const int L  = NB * C;                        // 153272
    const int nScan = (L + SCAN_CHUNK - 1) / SCAN_CHUNK;  // 150 (<=256)

    char* ws = (char*)d_ws;
    size_t off = 0;
    auto alloc = [&](size_t bytes) { void* p = ws + off; off += (bytes + 255) / 256 * 256; return p; };
    float* dis      = (float*)alloc((size_t)N * 4);
    int*   histT    = (int*)alloc((size_t)L * 4);
    int*   scanT    = (int*)alloc((size_t)L * 4);
    int*   blocksums= (int*)alloc(256 * 4);
    int*   blockoff = (int*)alloc(256 * 4);
    int*   binBase  = (int*)alloc((size_t)(NB + 1) * 4);
    int*   bucket   = (int*)alloc((size_t)E * 4);
    float* bufG     = (float*)alloc((size_t)N * HID * 4);
    float* bufA     = (float*)alloc((size_t)N * HID * 4);

    const int TPB = 256;
    const int* esrc = ei;
    const int* edst = ei + E;

    // binning (no global atomics anywhere)
    k_hist<<<C, TPB, 0, stream>>>(edst, E, C, NB, histT);
    k_scan1<<<nScan, TPB, 0, stream>>>(histT, L, scanT, blocksums);
    k_scan2<<<1, TPB, 0, stream>>>(blocksums, nScan, blockoff);
    k_scan3f<<<(L + TPB - 1) / TPB, TPB, 0, stream>>>(scanT, blockoff, L);
    k_binbase<<<(NB + 1 + TPB - 1) / TPB, TPB, 0, stream>>>(scanT, C, NB, E, binBase);
    k_scatterbin<<<C, TPB, 0, stream>>>(esrc, edst, E, C, NB, scanT, bucket);
    k_bindeg<<<NB, TPB, 0, stream>>>(binBase, bucket, dis, N);

    // layer 1
    k_xw1<<<2048, TPB, 0, stream>>>(x, W1, dis, bufG, N);
    k_aggbin1<<<NB, 512, 0, stream>>>(binBase, bucket, bufG, dis, b1, bufA, N);

    // layer 2 (+ fused head)
    k_xw2<<<2048, TPB, 0, stream>>>(bufA, W2, dis, bufG, N);
    k_aggbin2_head<<<NB, 512, 0, stream>>>(binBase, bucket, bufG, dis, b2, Wl, bl, out, N);
}

// Round 6
// 354.916 us; speedup vs baseline: 8.0153x; 8.0153x over previous
//
#include <hip/hip_runtime.h>

// GCN 2-layer + head.
// R6: atomic-free CSR build (bin histogram -> scan -> chunk scatter ->
//     per-bin LDS finalize) + R4's wave-per-row CSR aggregation.
// bucket word = (src<<7) | (dst&127), src < 2^17 so fits in 24 bits.

#define HID 64
#define INC 11
#define BINSH 7
#define BINW 128
#define MAXNB 800      // >= ceil(100000/128)=782
#define ECHUNK 16384
#define SCAN_CHUNK 1024
#define STAGE_MAX 6144 // per-bin staging cap (ints); bins ~4096 +- 64 here

// ---- per-chunk histogram of dst bins, stored transposed histT[b*C+c] ----
__global__ void k_hist(const int* __restrict__ dst, int E, int C, int NB,
                       int* __restrict__ histT) {
    __shared__ int h[MAXNB];
    int c = blockIdx.x, t = threadIdx.x;
    for (int i = t; i < NB; i += 256) h[i] = 0;
    __syncthreads();
    int base = c * ECHUNK;
    int end = min(base + ECHUNK, E);
    for (int i = base + t; i < end; i += 256)
        atomicAdd(&h[dst[i] >> BINSH], 1);
    __syncthreads();
    for (int b = t; b < NB; b += 256)
        histT[(size_t)b * C + c] = h[b];
}

// ---- generic 3-kernel exclusive scan (in-place safe), L <= 256*SCAN_CHUNK ----
__global__ void k_scan1(const int* __restrict__ in, int L,
                        int* __restrict__ part, int* __restrict__ blocksums) {
    __shared__ int lds[SCAN_CHUNK];
    __shared__ int tsum[256];
    int b = blockIdx.x, t = threadIdx.x;
    int base = b * SCAN_CHUNK;
    for (int i = t; i < SCAN_CHUNK; i += 256)
        lds[i] = (base + i < L) ? in[base + i] : 0;
    __syncthreads();
    int a0 = lds[t*4], a1 = lds[t*4+1], a2 = lds[t*4+2], a3 = lds[t*4+3];
    int ts = a0 + a1 + a2 + a3;
    tsum[t] = ts;
    __syncthreads();
    for (int off = 1; off < 256; off <<= 1) {
        int v = (t >= off) ? tsum[t - off] : 0;
        __syncthreads();
        tsum[t] += v;
        __syncthreads();
    }
    int excl = tsum[t] - ts;
    int i0 = base + t*4;
    if (i0     < L) part[i0]     = excl;
    if (i0 + 1 < L) part[i0 + 1] = excl + a0;
    if (i0 + 2 < L) part[i0 + 2] = excl + a0 + a1;
    if (i0 + 3 < L) part[i0 + 3] = excl + a0 + a1 + a2;
    if (t == 255) blocksums[b] = tsum[255];
}

__global__ void k_scan2(const int* __restrict__ blocksums, int nb, int* __restrict__ blockoff) {
    __shared__ int s[256];
    int t = threadIdx.x;
    s[t] = (t < nb) ? blocksums[t] : 0;
    __syncthreads();
    int mine = s[t];
    for (int off = 1; off < 256; off <<= 1) {
        int v = (t >= off) ? s[t - off] : 0;
        __syncthreads();
        s[t] += v;
        __syncthreads();
    }
    blockoff[t] = s[t] - mine;   // exclusive
}

__global__ void k_scan3f(int* __restrict__ part, const int* __restrict__ blockoff, int L) {
    int i = blockIdx.x * blockDim.x + threadIdx.x;
    if (i < L) part[i] += blockoff[i / SCAN_CHUNK];
}

// ---- scatter edges into bin-grouped bucket; rank via LDS atomic ----
__global__ void k_scatterbin(const int* __restrict__ src, const int* __restrict__ dst,
                             int E, int C, int NB, const int* __restrict__ scanT,
                             int* __restrict__ bucket) {
    __shared__ int cur[MAXNB];
    int c = blockIdx.x, t = threadIdx.x;
    for (int b = t; b < NB; b += 256) cur[b] = scanT[(size_t)b * C + c];
    __syncthreads();
    int base = c * ECHUNK;
    int end = min(base + ECHUNK, E);
    // 4 independent LDS-atomic chains in flight per thread
    for (int i = base + t; i < end; i += 1024) {
        int i1 = i + 256, i2 = i + 512, i3 = i + 768;
        int d0 = dst[i];
        int d1 = (i1 < end) ? dst[i1] : -1;
        int d2 = (i2 < end) ? dst[i2] : -1;
        int d3 = (i3 < end) ? dst[i3] : -1;
        int s0 = src[i];
        int s1 = (i1 < end) ? src[i1] : 0;
        int s2 = (i2 < end) ? src[i2] : 0;
        int s3 = (i3 < end) ? src[i3] : 0;
        int r0 = atomicAdd(&cur[d0 >> BINSH], 1);
        int r1 = (d1 >= 0) ? atomicAdd(&cur[d1 >> BINSH], 1) : 0;
        int r2 = (d2 >= 0) ? atomicAdd(&cur[d2 >> BINSH], 1) : 0;
        int r3 = (d3 >= 0) ? atomicAdd(&cur[d3 >> BINSH], 1) : 0;
        bucket[r0] = (s0 << BINSH) | (d0 & (BINW - 1));
        if (d1 >= 0) bucket[r1] = (s1 << BINSH) | (d1 & (BINW - 1));
        if (d2 >= 0) bucket[r2] = (s2 << BINSH) | (d2 & (BINW - 1));
        if (d3 >= 0) bucket[r3] = (s3 << BINSH) | (d3 & (BINW - 1));
    }
}

// ---- per-bin CSR finalize: local degree count, scan, staged coalesced write.
//      Produces csr (src sorted by dst), rowptr, dis. No global atomics. ----
__global__ void k_csrbuild(const int* __restrict__ scanT, int C, int NB, int E,
                           const int* __restrict__ bucket, int* __restrict__ csr,
                           int* __restrict__ rowptr, float* __restrict__ dis, int N) {
    __shared__ int cnt[BINW];
    __shared__ int ex[BINW];     // inclusive scan -> derive exclusive
    __shared__ int cur[BINW];
    __shared__ int stage[STAGE_MAX];
    int b = blockIdx.x, t = threadIdx.x;
    int s = scanT[(size_t)b * C];
    int e = (b + 1 < NB) ? scanT[(size_t)(b + 1) * C] : E;
    int len = e - s;
    if (t < BINW) cnt[t] = 0;
    __syncthreads();
    for (int p = s + t; p < e; p += 256)
        atomicAdd(&cnt[bucket[p] & (BINW - 1)], 1);
    __syncthreads();
    if (t < BINW) ex[t] = cnt[t];
    __syncthreads();
    for (int off = 1; off < BINW; off <<= 1) {
        int v = (t < BINW && t >= off) ? ex[t - off] : 0;
        __syncthreads();
        if (t < BINW) ex[t] += v;
        __syncthreads();
    }
    // ex[t] inclusive; exclusive = ex[t]-cnt[t]
    if (t < BINW) {
        int excl = ex[t] - cnt[t];
        cur[t] = excl;
        int n = b * BINW + t;
        if (n <= N) rowptr[n] = s + excl;      // n==N lands here in last bin
        if (n < N)  dis[n] = rsqrtf((float)(cnt[t] + 1));
    }
    __syncthreads();
    if (len <= STAGE_MAX) {
        for (int p = s + t; p < e; p += 256) {
            int w = bucket[p];
            int r = atomicAdd(&cur[w & (BINW - 1)], 1);
            stage[r] = w >> BINSH;
        }
        __syncthreads();
        for (int i = t; i < len; i += 256) csr[s + i] = stage[i];
    } else {
        for (int p = s + t; p < e; p += 256) {
            int w = bucket[p];
            int r = atomicAdd(&cur[w & (BINW - 1)], 1);
            csr[s + r] = w >> BINSH;
        }
    }
}

// ---- g[N,64] = dis[row] * (x[N,11] @ W1[11,64]) ----
__global__ void k_xw1(const float* __restrict__ x, const float* __restrict__ W1,
                      const float* __restrict__ dis, float* __restrict__ g, int N) {
    __shared__ float Ws[INC * HID];
    int t = threadIdx.x;
    for (int i = t; i < INC * HID; i += blockDim.x) Ws[i] = W1[i];
    __syncthreads();
    int c = t & 63;
    for (int row = blockIdx.x * 4 + (t >> 6); row < N; row += gridDim.x * 4) {
        float acc = 0.f;
        #pragma unroll
        for (int k = 0; k < INC; ++k) acc += x[row * INC + k] * Ws[k * HID + c];
        g[row * HID + c] = dis[row] * acc;
    }
}

// ---- g2[N,64] = dis[row] * (a[N,64] @ W2[64,64]), persistent blocks ----
__global__ void k_xw2(const float* __restrict__ in, const float* __restrict__ W2,
                      const float* __restrict__ dis, float* __restrict__ g, int N) {
    __shared__ float Ws[HID * HID];
    int t = threadIdx.x;
    for (int i = t; i < HID * HID; i += blockDim.x) Ws[i] = W2[i];
    __syncthreads();
    int c = t & 63;
    for (int row = blockIdx.x * 4 + (t >> 6); row < N; row += gridDim.x * 4) {
        const float* r = in + row * HID;
        float acc = 0.f;
        #pragma unroll
        for (int k = 0; k < HID; k += 4) {
            float4 rv = *(const float4*)(r + k);
            acc += rv.x * Ws[(k    ) * HID + c];
            acc += rv.y * Ws[(k + 1) * HID + c];
            acc += rv.z * Ws[(k + 2) * HID + c];
            acc += rv.w * Ws[(k + 3) * HID + c];
        }
        g[row * HID + c] = dis[row] * acc;
    }
}

// ---- neighbor-sum core, 4 gathers in flight ----
__device__ __forceinline__ float agg_row(const int* __restrict__ rowptr,
                                         const int* __restrict__ csr,
                                         const float* __restrict__ g,
                                         int row, int lane) {
    int s = rowptr[row], e = rowptr[row + 1];
    float acc = g[(size_t)row * HID + lane];   // self-loop (dis folded in g)
    for (int p = s; p < e; p += 64) {
        int idx = (p + lane < e) ? csr[p + lane] : 0;
        int cnt = min(64, e - p);
        int j = 0;
        for (; j + 3 < cnt; j += 4) {
            int s0 = __shfl(idx, j);
            int s1 = __shfl(idx, j + 1);
            int s2 = __shfl(idx, j + 2);
            int s3 = __shfl(idx, j + 3);
            float v0 = g[(size_t)s0 * HID + lane];
            float v1 = g[(size_t)s1 * HID + lane];
            float v2 = g[(size_t)s2 * HID + lane];
            float v3 = g[(size_t)s3 * HID + lane];
            acc += v0; acc += v1; acc += v2; acc += v3;
        }
        for (; j < cnt; ++j)
            acc += g[(size_t)__shfl(idx, j) * HID + lane];
    }
    return acc;
}

// ---- layer-1 aggregation: a[row] = relu(dis[row]*sum + b) ----
__global__ void k_agg1(const int* __restrict__ rowptr, const int* __restrict__ csr,
                       const float* __restrict__ g, const float* __restrict__ dis,
                       const float* __restrict__ b, float* __restrict__ outA, int N) {
    int lane = threadIdx.x & 63;
    int row = (blockIdx.x * blockDim.x + threadIdx.x) >> 6;
    if (row >= N) return;
    float acc = agg_row(rowptr, csr, g, row, lane);
    float v = dis[row] * acc + b[lane];
    outA[(size_t)row * HID + lane] = v > 0.f ? v : 0.f;
}

// ---- layer-2 aggregation fused with head ----
__global__ void k_agg2_head(const int* __restrict__ rowptr, const int* __restrict__ csr,
                            const float* __restrict__ g, const float* __restrict__ dis,
                            const float* __restrict__ b, const float* __restrict__ Wl,
                            const float* __restrict__ bl, float* __restrict__ out, int N) {
    int lane = threadIdx.x & 63;
    int row = (blockIdx.x * blockDim.x + threadIdx.x) >> 6;
    if (row >= N) return;
    float acc = agg_row(rowptr, csr, g, row, lane);
    float v = dis[row] * acc + b[lane];
    v = v > 0.f ? v : 0.f;
    v *= Wl[lane];
    #pragma unroll
    for (int off = 32; off > 0; off >>= 1) v += __shfl_down(v, off);
    if (lane == 0) out[row] = v + bl[0];
}

extern "C" void kernel_launch(void* const* d_in, const int* in_sizes, int n_in,
                              void* d_out, int out_size, void* d_ws, size_t ws_size,
                              hipStream_t stream) {
    const float* x  = (const float*)d_in[0];
    const int*   ei = (const int*)d_in[1];
    const float* W1 = (const float*)d_in[2];
    const float* b1 = (const float*)d_in[3];
    const float* W2 = (const float*)d_in[4];
    const float* b2 = (const float*)d_in[5];
    const float* Wl = (const float*)d_in[6];
    const float* bl = (const float*)d_in[7];
    float* out = (float*)d_out;

    const int N = in_sizes[0] / INC;    // 100000
    const int E = in_sizes[1] / 2;      // 3200000
    const int NB = (N + BINW - 1) / BINW;        // 782
    const int C  = (E + ECHUNK - 1) / ECHUNK;    // 196
    const int L  = NB * C;                        // 153272
    const int nScan = (L + SCAN_CHUNK - 1) / SCAN_CHUNK;  // 150 (<=256)

    char* ws = (char*)d_ws;
    size_t off = 0;
    auto alloc = [&](size_t bytes) { void* p = ws + off; off += (bytes + 255) / 256 * 256; return p; };
    int*   histT    = (int*)alloc((size_t)L * 4);     // scanned in place
    int*   blocksums= (int*)alloc(256 * 4);
    int*   blockoff = (int*)alloc(256 * 4);
    int*   rowptr   = (int*)alloc((size_t)(N + 1) * 4);
    float* dis      = (float*)alloc((size_t)N * 4);
    int*   csr      = (int*)alloc((size_t)E * 4);
    float* bufG     = (float*)alloc((size_t)N * HID * 4);
    float* bufA     = (float*)alloc((size_t)N * HID * 4);
    // bucket (E ints = 12.8 MB) aliases bufA: bucket's last read (k_csrbuild)
    // precedes bufA's first write (k_agg1).
    int* bucket = (int*)bufA;

    const int TPB = 256;
    const int* esrc = ei;
    const int* edst = ei + E;
    const int waveBlocks = ((size_t)N * 64 + TPB - 1) / TPB;   // wave per row

    // CSR build — zero global atomics
    k_hist<<<C, TPB, 0, stream>>>(edst, E, C, NB, histT);
    k_scan1<<<nScan, TPB, 0, stream>>>(histT, L, histT, blocksums);
    k_scan2<<<1, TPB, 0, stream>>>(blocksums, nScan, blockoff);
    k_scan3f<<<(L + TPB - 1) / TPB, TPB, 0, stream>>>(histT, blockoff, L);
    k_scatterbin<<<C, TPB, 0, stream>>>(esrc, edst, E, C, NB, histT, bucket);
    k_csrbuild<<<NB, TPB, 0, stream>>>(histT, C, NB, E, bucket, csr, rowptr, dis, N);

    // layer 1
    k_xw1<<<2048, TPB, 0, stream>>>(x, W1, dis, bufG, N);
    k_agg1<<<waveBlocks, TPB, 0, stream>>>(rowptr, csr, bufG, dis, b1, bufA, N);

    // layer 2 (+ fused head)
    k_xw2<<<2048, TPB, 0, stream>>>(bufA, W2, dis, bufG, N);
    k_agg2_head<<<waveBlocks, TPB, 0, stream>>>(rowptr, csr, bufG, dis, b2, Wl, bl, out, N);
}